// Round 5
// baseline (127.048 us; speedup 1.0000x reference)
//
#include <hip/hip_runtime.h>
#include <hip/hip_bf16.h>
#include <math.h>

// B,T,E,WIN,OC,VOCAB = 256,2048,128,5,128,50000
#define B_   256
#define T_   2048
#define E_   128
#define WIN_ 5
#define PAD_ 2
#define OC_  128
#define VOCAB1 50001
#define NT   8                    // 64-token tiles per block
#define TT   64
#define BTOK (NT * TT)            // 512 tokens per block
#define REAL_ROWS (TT + WIN_ - 1) // 68 rows incl. halo
#define ROWS 80                   // padded to 5 m-tiles of 16
#define ASTR 136                  // LDS row stride (bf16): 272B -> 2-way alias = free

#define NTAB_CH (VOCAB1 * E_ / 8) // 800016 short8 chunks

typedef __attribute__((ext_vector_type(8))) short short8;
typedef __attribute__((ext_vector_type(4))) float floatx4;

static __device__ __forceinline__ short f2bf(float f) {
    union { __hip_bfloat16 h; short s; } u;
    u.h = __float2bfloat16(f);
    return u.s;
}

__device__ __forceinline__ void atomicMaxFloat(float* addr, float v) {
    // works with 0xFFFFFFFF init pattern on both paths
    if (v >= 0.0f) atomicMax((int*)addr, __float_as_int(v));
    else           atomicMin((unsigned int*)addr, __float_as_uint(v));
}

__device__ __forceinline__ void conv_chunk(long i, const float* __restrict__ emb,
                                           const float* __restrict__ cnn_w,
                                           const float* __restrict__ att_w,
                                           short* __restrict__ tab, short* __restrict__ wsw,
                                           short* __restrict__ wsatt) {
    const float* src;
    short* dst;
    if (i < NTAB_CH) { src = emb; dst = tab; }
    else if ((i -= NTAB_CH) < OC_ * E_ / 8) { src = cnn_w; dst = wsw; }
    else if ((i -= OC_ * E_ / 8) < WIN_ * E_ / 8) { src = att_w; dst = wsatt; }
    else return;
    const float4* s = (const float4*)src + (size_t)i * 2;
    float4 a = s[0], b = s[1];
    short8 o = { f2bf(a.x), f2bf(a.y), f2bf(a.z), f2bf(a.w),
                 f2bf(b.x), f2bf(b.y), f2bf(b.z), f2bf(b.w) };
    *(short8*)(dst + (size_t)i * 8) = o;
}

// ---- prep (primary): bf16 table + cnn_w + att_w into ws (2 chunks/thread) ----
__global__ void prep_full(const float* __restrict__ emb, const float* __restrict__ cnn_w,
                          const float* __restrict__ att_w,
                          short* __restrict__ tab, short* __restrict__ wsw,
                          short* __restrict__ wsatt) {
    long i = (long)(blockIdx.x * 256 + threadIdx.x) * 2;
    conv_chunk(i,     emb, cnn_w, att_w, tab, wsw, wsatt);
    conv_chunk(i + 1, emb, cnn_w, att_w, tab, wsw, wsatt);
}

// ---- prep (fallback): weights only ----
__global__ void prep_small(const float* __restrict__ cnn_w, const float* __restrict__ att_w,
                           short* __restrict__ wsw, short* __restrict__ wsatt) {
    int i = blockIdx.x * 256 + threadIdx.x;
    if (i < OC_ * E_)  wsw[i]   = f2bf(cnn_w[i]);
    if (i < WIN_ * E_) wsatt[i] = f2bf(att_w[i]);
}

template <bool TAB_BF16>
__launch_bounds__(256, 4)
__global__ void local_attn_main(const int* __restrict__ x,
                                const short* __restrict__ tab,
                                const float* __restrict__ emb,
                                const float* __restrict__ att_b_p,
                                const short* __restrict__ wsw,
                                const short* __restrict__ wsatt,
                                const float* __restrict__ cnn_b,
                                float* __restrict__ out) {
    __shared__ short sh_a[ROWS * ASTR];     // 21760 B (one tile of bf16 embed rows)
    __shared__ short sh_att[16 * ASTR];     // 4352 B  (taps 0-4 real, rest zero)
    __shared__ float sh_r[ROWS * 8];        // 2560 B
    __shared__ float sh_score[TT];          // 256 B
    __shared__ int   sh_idx[NT * ROWS];     // 2560 B   -> 31.5 KB total

    const int tid  = threadIdx.x;
    const int lane = tid & 63;
    const int w    = tid >> 6;              // wave 0..3 -> o-range [w*32, w*32+32)
    const int b    = blockIdx.y;
    const int t0   = blockIdx.x * BTOK;
    const int l15  = lane & 15;
    const int quad = lane >> 4;
    const int rbase = tid >> 4;             // gather rows rbase+16k, chunk c
    const int c     = tid & 15;

    // ---- stage all tile indices once ----
    for (int i = tid; i < NT * ROWS; i += 256) {
        int tile = i / ROWS, row = i - tile * ROWS;
        int t = t0 + tile * TT + row - PAD_;
        sh_idx[i] = (row < REAL_ROWS && t >= 0 && t < T_) ? x[b * T_ + t] : -1;
    }
    // ---- stage att_w (zero-padded to 16 taps) ----
    {
        int o = tid >> 4, cc = tid & 15;
        short8 v = (short8){0,0,0,0,0,0,0,0};
        if (o < WIN_) v = *(const short8*)(wsatt + o * E_ + cc * 8);
        *(short8*)(&sh_att[o * ASTR + cc * 8]) = v;
    }
    // ---- B fragments: wave covers 32 cols: Bf[j][ks], j<2 ----
    short8 Bf[2][4];
    #pragma unroll
    for (int j = 0; j < 2; j++)
        #pragma unroll
        for (int ks = 0; ks < 4; ks++)
            Bf[j][ks] = *(const short8*)(wsw + (size_t)(w * 32 + j * 16 + l15) * E_ + ks * 32 + quad * 8);
    __syncthreads();

    // ---- gather + commit tile 0 ----
    short8 g[5];
    #pragma unroll
    for (int k = 0; k < 5; k++) {
        int row = rbase + 16 * k;
        int idx = sh_idx[row];
        short8 v = (short8){0,0,0,0,0,0,0,0};
        if (idx >= 0) {
            if (TAB_BF16) v = *(const short8*)(tab + (size_t)idx * E_ + c * 8);
            else {
                const float4* p = (const float4*)(emb + (size_t)idx * E_ + c * 8);
                float4 p0 = p[0], p1 = p[1];
                v = (short8){ f2bf(p0.x), f2bf(p0.y), f2bf(p0.z), f2bf(p0.w),
                              f2bf(p1.x), f2bf(p1.y), f2bf(p1.z), f2bf(p1.w) };
            }
        }
        g[k] = v;
    }
    #pragma unroll
    for (int k = 0; k < 5; k++)
        *(short8*)(&sh_a[(rbase + 16 * k) * ASTR + c * 8]) = g[k];
    __syncthreads();

    const float attb = att_b_p[0];
    float mm[2] = { -INFINITY, -INFINITY };

    for (int it = 0; it < NT; it++) {
        // 1) scores via MFMA -> sh_r
        for (int mt = w; mt < 5; mt += 4) {
            floatx4 acc = (floatx4){0.f, 0.f, 0.f, 0.f};
            #pragma unroll
            for (int ks = 0; ks < 4; ks++) {
                short8 a  = *(const short8*)(&sh_a[(mt * 16 + l15) * ASTR + ks * 32 + quad * 8]);
                short8 bs = *(const short8*)(&sh_att[l15 * ASTR + ks * 32 + quad * 8]);
                acc = __builtin_amdgcn_mfma_f32_16x16x32_bf16(a, bs, acc, 0, 0, 0);
            }
            if (l15 < 8) {
                #pragma unroll
                for (int r = 0; r < 4; r++)
                    sh_r[(mt * 16 + quad * 4 + r) * 8 + l15] = acc[r];
            }
        }
        __syncthreads();                       // (a) sh_r ready; drains nothing (no loads in flight)

        // 2) issue next tile's gathers AFTER the barrier: they stay in flight
        //    across sigmoid + 32 MFMAs and are only drained at barrier (b).
        if (it + 1 < NT) {
            const int* idxp = &sh_idx[(it + 1) * ROWS];
            #pragma unroll
            for (int k = 0; k < 5; k++) {
                int idx = idxp[rbase + 16 * k];
                short8 v = (short8){0,0,0,0,0,0,0,0};
                if (idx >= 0) {
                    if (TAB_BF16) v = *(const short8*)(tab + (size_t)idx * E_ + c * 8);
                    else {
                        const float4* p = (const float4*)(emb + (size_t)idx * E_ + c * 8);
                        float4 p0 = p[0], p1 = p[1];
                        v = (short8){ f2bf(p0.x), f2bf(p0.y), f2bf(p0.z), f2bf(p0.w),
                                      f2bf(p1.x), f2bf(p1.y), f2bf(p1.z), f2bf(p1.w) };
                    }
                }
                g[k] = v;
            }
        }

        // 3) window sum + sigmoid
        if (tid < TT) {
            float s = attb;
            #pragma unroll
            for (int k = 0; k < WIN_; k++) s += sh_r[(tid + k) * 8 + k];
            sh_score[tid] = 1.0f / (1.0f + __expf(-s));
        }

        // 4) GEMM: full 64 rows x 32 cols per wave
        floatx4 acc[4][2];
        #pragma unroll
        for (int i = 0; i < 4; i++)
            #pragma unroll
            for (int j = 0; j < 2; j++) acc[i][j] = (floatx4){0.f, 0.f, 0.f, 0.f};

        #pragma unroll
        for (int ks = 0; ks < 4; ks++) {
            int ko = ks * 32 + quad * 8;
            #pragma unroll
            for (int i = 0; i < 4; i++) {
                short8 ai = *(const short8*)(&sh_a[(PAD_ + i * 16 + l15) * ASTR + ko]);
                acc[i][0] = __builtin_amdgcn_mfma_f32_16x16x32_bf16(ai, Bf[0][ks], acc[i][0], 0, 0, 0);
                acc[i][1] = __builtin_amdgcn_mfma_f32_16x16x32_bf16(ai, Bf[1][ks], acc[i][1], 0, 0, 0);
            }
        }
        __syncthreads();                       // (b) sh_score ready; sh_a reads done

        // 5) epilogue: scale by score, fold into running max
        #pragma unroll
        for (int i = 0; i < 4; i++) {
            #pragma unroll
            for (int r = 0; r < 4; r++) {
                float sc = sh_score[i * 16 + quad * 4 + r];
                mm[0] = fmaxf(mm[0], sc * acc[i][0][r]);
                mm[1] = fmaxf(mm[1], sc * acc[i][1][r]);
            }
        }

        // 6) commit next tile (loads have landed by now; ds_write waits only on vmcnt)
        if (it + 1 < NT) {
            #pragma unroll
            for (int k = 0; k < 5; k++)
                *(short8*)(&sh_a[(rbase + 16 * k) * ASTR + c * 8]) = g[k];
            __syncthreads();                   // (c) sh_a ready for next iter
        }
    }

    // ---- final: quad-reduce, tanh(+bias), atomicMax ----
    #pragma unroll
    for (int j = 0; j < 2; j++) {
        float m = mm[j];
        m = fmaxf(m, __shfl_xor(m, 16));
        m = fmaxf(m, __shfl_xor(m, 32));
        if (lane < 16) {
            int o = w * 32 + j * 16 + lane;
            atomicMaxFloat(&out[b * OC_ + o], tanhf(m + cnn_b[o]));
        }
    }
}

extern "C" void kernel_launch(void* const* d_in, const int* in_sizes, int n_in,
                              void* d_out, int out_size, void* d_ws, size_t ws_size,
                              hipStream_t stream) {
    const int*   x     = (const int*)d_in[0];
    const float* emb   = (const float*)d_in[1];
    const float* att_w = (const float*)d_in[2];
    const float* att_b = (const float*)d_in[3];
    const float* cnn_w = (const float*)d_in[4];
    const float* cnn_b = (const float*)d_in[5];
    float* out = (float*)d_out;

    // out init: 0xFFFFFFFF is the identity element for the int/uint atomic-max trick
    hipMemsetAsync(d_out, 0xFF, (size_t)B_ * OC_ * sizeof(float), stream);

    const size_t tab_elems = (size_t)VOCAB1 * E_;
    const size_t need = tab_elems * 2 + OC_ * E_ * 2 + WIN_ * E_ * 2 + 64;

    dim3 grid(T_ / BTOK, B_);   // (4, 256) = 1024 blocks = 4 blocks/CU exactly

    if (ws_size >= need) {
        short* tab    = (short*)d_ws;
        short* ws_w   = tab + tab_elems;
        short* ws_att = ws_w + OC_ * E_;
        long total = (NTAB_CH + OC_ * E_ / 8 + WIN_ * E_ / 8 + 1) / 2;
        prep_full<<<(int)((total + 255) / 256), 256, 0, stream>>>(emb, cnn_w, att_w, tab, ws_w, ws_att);
        local_attn_main<true><<<grid, 256, 0, stream>>>(x, tab, emb, att_b, ws_w, ws_att, cnn_b, out);
    } else {
        short* ws_w   = (short*)d_ws;
        short* ws_att = ws_w + OC_ * E_;
        prep_small<<<16, 256, 0, stream>>>(cnn_w, att_w, ws_w, ws_att);
        local_attn_main<false><<<grid, 256, 0, stream>>>(x, (const short*)nullptr, emb, att_b, ws_w, ws_att, cnn_b, out);
    }
}